// Round 10
// baseline (173.772 us; speedup 1.0000x reference)
//
#include <hip/hip_runtime.h>
#include <hip/hip_cooperative_groups.h>

namespace cg = cooperative_groups;

#define B   16
#define C1  256          // channels per input
#define C2  512          // total channels after concat
#define HW  4096         // 64*64 pixels per channel
#define TCHUNK 32        // 128-pixel chunks per image

typedef float vf4 __attribute__((ext_vector_type(4)));

__device__ __forceinline__ const vf4* chan_base(
    const float* __restrict__ x1, const float* __restrict__ x2, int b, int c)
{
    return (const vf4*)((c < C1) ? (x1 + (size_t)(b * C1 + c) * HW)
                                 : (x2 + (size_t)(b * C1 + (c - C1)) * HW));
}

// ---------------------------------------------------------------------------
// Single cooperative kernel, 512 blocks x 256 threads (2 blocks/CU).
// Block (b, chunk) owns 128 pixels of image b across ALL phases -> its
// phase-3 re-reads hit the lines phase 1 pulled into the SAME XCD's L2.
//
// phase 1: cold sweep (best-measured shape): 8 channel-groups x 32 slots,
//          4-way ILP loads, per-channel width-32 shuffle reduce -> partials;
//          per-pixel totals accumulated in registers (tt stays in-register).
// grid.sync
// phase 2: per-block replicated rank-sort of this image's pooled sums
//          (reads 64 KB warm partials; idx list lives in LDS only).
// phase 3: copy k-1 head channels in rank order, accumulate head-sum,
//          write channel k-1 = tt - head_sum. Tail never re-read.
// ---------------------------------------------------------------------------
__global__ __launch_bounds__(256) void fused_kernel(
    const float* __restrict__ x1, const float* __restrict__ x2,
    float* __restrict__ partials,     // [B][TCHUNK][C2]  (1 MB ws)
    float* __restrict__ out, int k)
{
    cg::grid_group grid = cg::this_grid();

    int bid   = blockIdx.x;          // 0..511
    int b     = bid / TCHUNK;
    int chunk = bid % TCHUNK;
    int t     = threadIdx.x;
    int g     = t >> 5;              // channel group 0..7
    int slot  = t & 31;              // f4-slot within 128-pixel chunk
    int off   = chunk * 32 + slot;   // f4 index within channel

    __shared__ vf4   red[8][32];     // 4 KB
    __shared__ float sp[C2];         // 2 KB
    __shared__ int   idxl[C2];       // 2 KB

    // ================= phase 1: cold sweep =================
    float* pp = partials + (size_t)(b * TCHUNK + chunk) * C2;
    vf4 t0 = (vf4)(0.f), t1 = (vf4)(0.f), t2 = (vf4)(0.f), t3 = (vf4)(0.f);

    for (int j = 0; j < 64; j += 4) {
        int c0 = (j + 0) * 8 + g, c1 = (j + 1) * 8 + g;
        int c2 = (j + 2) * 8 + g, c3 = (j + 3) * 8 + g;
        vf4 v0 = chan_base(x1, x2, b, c0)[off];
        vf4 v1 = chan_base(x1, x2, b, c1)[off];
        vf4 v2 = chan_base(x1, x2, b, c2)[off];
        vf4 v3 = chan_base(x1, x2, b, c3)[off];
        t0 += v0; t1 += v1; t2 += v2; t3 += v3;

        float h0 = (v0.x + v0.y) + (v0.z + v0.w);
        float h1 = (v1.x + v1.y) + (v1.z + v1.w);
        float h2 = (v2.x + v2.y) + (v2.z + v2.w);
        float h3 = (v3.x + v3.y) + (v3.z + v3.w);
        #pragma unroll
        for (int s = 16; s > 0; s >>= 1) {
            h0 += __shfl_down(h0, s, 32);
            h1 += __shfl_down(h1, s, 32);
            h2 += __shfl_down(h2, s, 32);
            h3 += __shfl_down(h3, s, 32);
        }
        if (slot == 0) {
            pp[c0] = h0; pp[c1] = h1; pp[c2] = h2; pp[c3] = h3;
        }
    }

    red[g][slot] = (t0 + t1) + (t2 + t3);
    __syncthreads();
    vf4 tt = (vf4)(0.f);             // per-pixel total, register-resident
    if (g == 0) {
        #pragma unroll
        for (int gg = 0; gg < 8; ++gg)
            tt += red[gg][slot];
    }

    __threadfence();                 // partials visible device-wide
    grid.sync();

    // ================= phase 2: replicated rank-sort =================
    {
        int cA = t, cB = t + 256;
        const float* pb = partials + (size_t)b * TCHUNK * C2;
        float vA = 0.f, vB = 0.f;
        #pragma unroll
        for (int ch = 0; ch < TCHUNK; ++ch) {
            vA += pb[ch * C2 + cA];
            vB += pb[ch * C2 + cB];
        }
        sp[cA] = vA; sp[cB] = vB;
        __syncthreads();
        int rA = 0, rB = 0;
        for (int j = 0; j < C2; ++j) {
            float u = sp[j];
            rA += (u > vA) || (u == vA && j < cA);
            rB += (u > vB) || (u == vB && j < cB);
        }
        idxl[rA] = cA;
        idxl[rB] = cB;
        __syncthreads();
    }

    // ================= phase 3: output =================
    int nh = k - 1;                  // head channels copied verbatim
    vf4 a0 = (vf4)(0.f), a1 = (vf4)(0.f), a2 = (vf4)(0.f), a3 = (vf4)(0.f);
    const size_t ob = (size_t)b * k;
    int r = g;
    for (; r + 24 < nh; r += 32) {
        int c0 = idxl[r], c1 = idxl[r + 8], c2 = idxl[r + 16], c3 = idxl[r + 24];
        vf4 v0 = chan_base(x1, x2, b, c0)[off];
        vf4 v1 = chan_base(x1, x2, b, c1)[off];
        vf4 v2 = chan_base(x1, x2, b, c2)[off];
        vf4 v3 = chan_base(x1, x2, b, c3)[off];
        ((vf4*)(out + (ob + r     ) * HW))[off] = v0;
        ((vf4*)(out + (ob + r +  8) * HW))[off] = v1;
        ((vf4*)(out + (ob + r + 16) * HW))[off] = v2;
        ((vf4*)(out + (ob + r + 24) * HW))[off] = v3;
        a0 += v0; a1 += v1; a2 += v2; a3 += v3;
    }
    for (; r < nh; r += 8) {
        int c0 = idxl[r];
        vf4 v0 = chan_base(x1, x2, b, c0)[off];
        ((vf4*)(out + (ob + r) * HW))[off] = v0;
        a0 += v0;
    }

    __syncthreads();                 // red[] reuse
    red[g][slot] = (a0 + a1) + (a2 + a3);
    __syncthreads();
    if (g == 0) {
        vf4 hsum = (vf4)(0.f);
        #pragma unroll
        for (int gg = 0; gg < 8; ++gg)
            hsum += red[gg][slot];
        ((vf4*)(out + (ob + (k - 1)) * HW))[off] = tt - hsum;
    }
}

// ---------------------------------------------------------------------------
extern "C" void kernel_launch(void* const* d_in, const int* in_sizes, int n_in,
                              void* d_out, int out_size, void* d_ws, size_t ws_size,
                              hipStream_t stream)
{
    const float* x1 = (const float*)d_in[0];
    const float* x2 = (const float*)d_in[1];
    float* out = (float*)d_out;

    int k = out_size / (B * HW);               // = 256

    float* partials = (float*)d_ws;            // B*TCHUNK*C2 floats = 1 MB

    void* args[] = { (void*)&x1, (void*)&x2, (void*)&partials,
                     (void*)&out, (void*)&k };
    hipLaunchCooperativeKernel((const void*)fused_kernel,
                               dim3(B * TCHUNK), dim3(256),
                               args, 0, stream);
}

// Round 11
// 70.918 us; speedup vs baseline: 2.4503x; 2.4503x over previous
//
#include <hip/hip_runtime.h>

#define B   16
#define C1  256          // channels per input
#define C2  512          // total channels after concat
#define HW  4096         // 64*64 pixels per channel
#define NSLAB 32         // 16-channel slabs per image (contiguous 256 KB)
#define TCHUNK 32        // 128-pixel chunks per image (output kernel)

typedef float vf4 __attribute__((ext_vector_type(4)));

__device__ __forceinline__ const vf4* chan_base(
    const float* __restrict__ x1, const float* __restrict__ x2, int b, int c)
{
    return (const vf4*)((c < C1) ? (x1 + (size_t)(b * C1 + c) * HW)
                                 : (x2 + (size_t)(b * C1 + (c - C1)) * HW));
}

// ===========================================================================
// FAST PATH
// ===========================================================================
// K1: slab reduce. Block = (b, slab of 16 contiguous channels) -> each block
// streams a CONTIGUOUS 256 KB region (DRAM row-friendly). Hot loop is pure
// load+add into registers: 4 vf4 per-pixel accumulators + 16 per-channel
// scalars. No LDS, no shuffles, no cross-block partials for pooled.
// Outputs: pooled[b*C2+c] (complete), pixpart[b][slab][pix].
// ---------------------------------------------------------------------------
__global__ __launch_bounds__(256) void slab_reduce_kernel(
    const float* __restrict__ x1, const float* __restrict__ x2,
    float* __restrict__ pooled,      // [B*C2]
    float* __restrict__ pixpart)     // [B][NSLAB][HW]
{
    int bid = blockIdx.x;            // 0..511
    int b   = bid >> 5;
    int s   = bid & 31;
    int t   = threadIdx.x;

    const float* base = (s < 16)
        ? x1 + ((size_t)b * C1 + s * 16) * HW
        : x2 + ((size_t)b * C1 + (s - 16) * 16) * HW;
    const vf4* p = (const vf4*)base;     // 16 channels x 1024 vf4, contiguous

    vf4 px0 = (vf4)(0.f), px1 = px0, px2 = px0, px3 = px0;
    float h[16];
    #pragma unroll
    for (int j = 0; j < 16; ++j) h[j] = 0.f;

    #pragma unroll
    for (int j = 0; j < 16; ++j) {
        vf4 v0 = p[j * 1024 + t];
        vf4 v1 = p[j * 1024 + t + 256];
        vf4 v2 = p[j * 1024 + t + 512];
        vf4 v3 = p[j * 1024 + t + 768];
        px0 += v0; px1 += v1; px2 += v2; px3 += v3;
        h[j] += ((v0.x + v0.y) + (v0.z + v0.w))
              + ((v1.x + v1.y) + (v1.z + v1.w))
              + ((v2.x + v2.y) + (v2.z + v2.w))
              + ((v3.x + v3.y) + (v3.z + v3.w));
    }

    // per-pixel slab partial -> ws
    vf4* pp = (vf4*)(pixpart + ((size_t)b * NSLAB + s) * HW);
    pp[t] = px0; pp[t + 256] = px1; pp[t + 512] = px2; pp[t + 768] = px3;

    // per-channel pooled sums (block-complete)
    __shared__ float hacc[16][258];      // 258 stride dodges bank conflicts
    #pragma unroll
    for (int j = 0; j < 16; ++j) hacc[j][t] = h[j];
    __syncthreads();
    if (t < 16) {
        float sum = 0.f;
        for (int i = 0; i < 256; ++i) sum += hacc[t][i];
        pooled[b * C2 + s * 16 + t] = sum;
    }
}

// ---------------------------------------------------------------------------
// K2: output. Block = (b, 128-pixel chunk). Replicated rank-sort from pooled
// (2 KB, warm), head copy in rank order, channel k-1 = total - headsum where
// total comes from summing the 32 slab pixel-partials.
// ---------------------------------------------------------------------------
__global__ __launch_bounds__(256) void output2_kernel(
    const float* __restrict__ x1, const float* __restrict__ x2,
    const float* __restrict__ pooled, const float* __restrict__ pixpart,
    float* __restrict__ out, int k)
{
    int bid   = blockIdx.x;
    int b     = bid >> 5;
    int chunk = bid & 31;
    int t     = threadIdx.x;
    int g     = t >> 5;
    int slot  = t & 31;
    int off   = chunk * 32 + slot;

    __shared__ float sp[C2];
    __shared__ int   idxl[C2];
    __shared__ vf4   red[8][32];

    // replicated stable descending rank-sort (identical in every block)
    {
        int cA = t, cB = t + 256;
        float vA = pooled[b * C2 + cA];
        float vB = pooled[b * C2 + cB];
        sp[cA] = vA; sp[cB] = vB;
        __syncthreads();
        int rA = 0, rB = 0;
        for (int j = 0; j < C2; ++j) {
            float u = sp[j];
            rA += (u > vA) || (u == vA && j < cA);
            rB += (u > vB) || (u == vB && j < cB);
        }
        idxl[rA] = cA;
        idxl[rB] = cB;
        __syncthreads();
    }

    int nh = k - 1;                  // head channels (ranks 0..k-2)
    vf4 a0 = (vf4)(0.f), a1 = (vf4)(0.f), a2 = (vf4)(0.f), a3 = (vf4)(0.f);
    const size_t ob = (size_t)b * k;
    int r = g;
    for (; r + 24 < nh; r += 32) {
        int c0 = idxl[r], c1 = idxl[r + 8], c2 = idxl[r + 16], c3 = idxl[r + 24];
        vf4 v0 = chan_base(x1, x2, b, c0)[off];
        vf4 v1 = chan_base(x1, x2, b, c1)[off];
        vf4 v2 = chan_base(x1, x2, b, c2)[off];
        vf4 v3 = chan_base(x1, x2, b, c3)[off];
        ((vf4*)(out + (ob + r     ) * HW))[off] = v0;
        ((vf4*)(out + (ob + r +  8) * HW))[off] = v1;
        ((vf4*)(out + (ob + r + 16) * HW))[off] = v2;
        ((vf4*)(out + (ob + r + 24) * HW))[off] = v3;
        a0 += v0; a1 += v1; a2 += v2; a3 += v3;
    }
    for (; r < nh; r += 8) {
        int c0 = idxl[r];
        vf4 v0 = chan_base(x1, x2, b, c0)[off];
        ((vf4*)(out + (ob + r) * HW))[off] = v0;
        a0 += v0;
    }

    // this thread's share of (total - headsum): slabs g, g+8, g+16, g+24
    vf4 tp = (vf4)(0.f);
    {
        const vf4* pb = (const vf4*)(pixpart + (size_t)b * NSLAB * HW);
        #pragma unroll
        for (int m = 0; m < 4; ++m)
            tp += pb[(size_t)(g + m * 8) * 1024 + off];
    }

    red[g][slot] = tp - ((a0 + a1) + (a2 + a3));
    __syncthreads();
    if (g == 0) {
        vf4 res = (vf4)(0.f);
        #pragma unroll
        for (int gg = 0; gg < 8; ++gg)
            res += red[gg][slot];
        ((vf4*)(out + (ob + (k - 1)) * HW))[off] = res;
    }
}

// ===========================================================================
// FALLBACK PATH (round-9 trio; used only if ws_size < fast-path need)
// ===========================================================================
__global__ __launch_bounds__(256) void fb_reduce_kernel(
    const float* __restrict__ x1, const float* __restrict__ x2,
    float* __restrict__ total, float* __restrict__ partials)
{
    int bid   = blockIdx.x;
    int b     = bid / TCHUNK;
    int chunk = bid % TCHUNK;
    int t     = threadIdx.x;
    int g     = t >> 5;
    int slot  = t & 31;
    int off   = chunk * 32 + slot;

    float* pp = partials + (size_t)(b * TCHUNK + chunk) * C2;
    vf4 t0 = (vf4)(0.f), t1 = (vf4)(0.f), t2 = (vf4)(0.f), t3 = (vf4)(0.f);

    for (int j = 0; j < 64; j += 4) {
        int c0 = (j + 0) * 8 + g, c1 = (j + 1) * 8 + g;
        int c2 = (j + 2) * 8 + g, c3 = (j + 3) * 8 + g;
        vf4 v0 = chan_base(x1, x2, b, c0)[off];
        vf4 v1 = chan_base(x1, x2, b, c1)[off];
        vf4 v2 = chan_base(x1, x2, b, c2)[off];
        vf4 v3 = chan_base(x1, x2, b, c3)[off];
        t0 += v0; t1 += v1; t2 += v2; t3 += v3;
        float h0 = (v0.x + v0.y) + (v0.z + v0.w);
        float h1 = (v1.x + v1.y) + (v1.z + v1.w);
        float h2 = (v2.x + v2.y) + (v2.z + v2.w);
        float h3 = (v3.x + v3.y) + (v3.z + v3.w);
        #pragma unroll
        for (int s = 16; s > 0; s >>= 1) {
            h0 += __shfl_down(h0, s, 32);
            h1 += __shfl_down(h1, s, 32);
            h2 += __shfl_down(h2, s, 32);
            h3 += __shfl_down(h3, s, 32);
        }
        if (slot == 0) { pp[c0] = h0; pp[c1] = h1; pp[c2] = h2; pp[c3] = h3; }
    }

    __shared__ vf4 red[8][32];
    red[g][slot] = (t0 + t1) + (t2 + t3);
    __syncthreads();
    if (g == 0) {
        vf4 r = (vf4)(0.f);
        #pragma unroll
        for (int gg = 0; gg < 8; ++gg) r += red[gg][slot];
        ((vf4*)(total + (size_t)b * HW))[off] = r;
    }
}

__global__ __launch_bounds__(512) void fb_sort_kernel(
    const float* __restrict__ partials, int* __restrict__ idx)
{
    int b = blockIdx.x;
    int t = threadIdx.x;
    const float* pp = partials + (size_t)b * TCHUNK * C2 + t;
    float v = 0.f;
    #pragma unroll
    for (int ch = 0; ch < TCHUNK; ++ch) v += pp[ch * C2];
    __shared__ float sp[C2];
    sp[t] = v;
    __syncthreads();
    int rank = 0;
    for (int j = 0; j < C2; ++j) {
        float u = sp[j];
        rank += (u > v) || (u == v && j < t);
    }
    idx[b * C2 + rank] = t;
}

__global__ __launch_bounds__(256) void fb_output_kernel(
    const float* __restrict__ x1, const float* __restrict__ x2,
    const int* __restrict__ idx, const float* __restrict__ total,
    float* __restrict__ out, int k)
{
    int bid   = blockIdx.x;
    int b     = bid / TCHUNK;
    int chunk = bid % TCHUNK;
    int t     = threadIdx.x;
    int g     = t >> 5;
    int slot  = t & 31;
    int off   = chunk * 32 + slot;
    int nh    = k - 1;

    __shared__ int ch[C2 / 2];
    __shared__ vf4 red[8][32];
    for (int i = t; i < nh; i += 256) ch[i] = idx[b * C2 + i];
    __syncthreads();

    vf4 a0 = (vf4)(0.f), a1 = (vf4)(0.f), a2 = (vf4)(0.f), a3 = (vf4)(0.f);
    const size_t ob = (size_t)b * k;
    int r = g;
    for (; r + 24 < nh; r += 32) {
        int c0 = ch[r], c1 = ch[r + 8], c2 = ch[r + 16], c3 = ch[r + 24];
        vf4 v0 = chan_base(x1, x2, b, c0)[off];
        vf4 v1 = chan_base(x1, x2, b, c1)[off];
        vf4 v2 = chan_base(x1, x2, b, c2)[off];
        vf4 v3 = chan_base(x1, x2, b, c3)[off];
        ((vf4*)(out + (ob + r     ) * HW))[off] = v0;
        ((vf4*)(out + (ob + r +  8) * HW))[off] = v1;
        ((vf4*)(out + (ob + r + 16) * HW))[off] = v2;
        ((vf4*)(out + (ob + r + 24) * HW))[off] = v3;
        a0 += v0; a1 += v1; a2 += v2; a3 += v3;
    }
    for (; r < nh; r += 8) {
        int c0 = ch[r];
        vf4 v0 = chan_base(x1, x2, b, c0)[off];
        ((vf4*)(out + (ob + r) * HW))[off] = v0;
        a0 += v0;
    }

    red[g][slot] = (a0 + a1) + (a2 + a3);
    __syncthreads();
    if (g == 0) {
        vf4 hsum = (vf4)(0.f);
        #pragma unroll
        for (int gg = 0; gg < 8; ++gg) hsum += red[gg][slot];
        vf4 tt = ((const vf4*)(total + (size_t)b * HW))[off];
        ((vf4*)(out + (ob + (k - 1)) * HW))[off] = tt - hsum;
    }
}

// ---------------------------------------------------------------------------
extern "C" void kernel_launch(void* const* d_in, const int* in_sizes, int n_in,
                              void* d_out, int out_size, void* d_ws, size_t ws_size,
                              hipStream_t stream)
{
    const float* x1 = (const float*)d_in[0];
    const float* x2 = (const float*)d_in[1];
    float* out = (float*)d_out;

    int k = out_size / (B * HW);               // = 256

    size_t need_fast = (size_t)B * C2 * sizeof(float)              // pooled 32 KB
                     + (size_t)B * NSLAB * HW * sizeof(float);     // pixpart 8 MB

    if (ws_size >= need_fast) {
        float* pooled  = (float*)d_ws;
        float* pixpart = pooled + B * C2;
        slab_reduce_kernel<<<B * NSLAB, 256, 0, stream>>>(x1, x2, pooled, pixpart);
        output2_kernel<<<B * TCHUNK, 256, 0, stream>>>(x1, x2, pooled, pixpart, out, k);
    } else {
        int*   idx      = (int*)d_ws;
        float* total    = (float*)((char*)d_ws + B * C2 * sizeof(int));
        float* partials = total + (size_t)B * HW;
        fb_reduce_kernel<<<B * TCHUNK, 256, 0, stream>>>(x1, x2, total, partials);
        fb_sort_kernel<<<B, 512, 0, stream>>>(partials, idx);
        fb_output_kernel<<<B * TCHUNK, 256, 0, stream>>>(x1, x2, idx, total, out, k);
    }
}

// Round 12
// 63.160 us; speedup vs baseline: 2.7513x; 1.1228x over previous
//
#include <hip/hip_runtime.h>

#define B   16
#define C1  256          // channels per input
#define C2  512          // total channels after concat
#define HW  4096         // 64*64 pixels per channel
#define TCHUNK 32        // 128-pixel chunks per image

typedef float vf4 __attribute__((ext_vector_type(4)));

__device__ __forceinline__ const vf4* chan_base(
    const float* __restrict__ x1, const float* __restrict__ x2, int b, int c)
{
    return (const vf4*)((c < C1) ? (x1 + (size_t)(b * C1 + c) * HW)
                                 : (x2 + (size_t)(b * C1 + (c - C1)) * HW));
}

// ---------------------------------------------------------------------------
// K1: reduce (round-7/9 best-measured shape, unchanged).
// Block = (b, 128-pixel chunk); 8 channel-groups x 32 slots; 4-way ILP;
// per-channel width-32 shuffle reduce -> partials; per-pixel totals -> total.
// ---------------------------------------------------------------------------
__global__ __launch_bounds__(256) void reduce_kernel(
    const float* __restrict__ x1, const float* __restrict__ x2,
    float* __restrict__ total, float* __restrict__ partials)
{
    int bid   = blockIdx.x;
    int b     = bid / TCHUNK;
    int chunk = bid % TCHUNK;
    int t     = threadIdx.x;
    int g     = t >> 5;
    int slot  = t & 31;
    int off   = chunk * 32 + slot;

    float* pp = partials + (size_t)(b * TCHUNK + chunk) * C2;
    vf4 t0 = (vf4)(0.f), t1 = (vf4)(0.f), t2 = (vf4)(0.f), t3 = (vf4)(0.f);

    for (int j = 0; j < 64; j += 4) {
        int c0 = (j + 0) * 8 + g, c1 = (j + 1) * 8 + g;
        int c2 = (j + 2) * 8 + g, c3 = (j + 3) * 8 + g;
        vf4 v0 = chan_base(x1, x2, b, c0)[off];
        vf4 v1 = chan_base(x1, x2, b, c1)[off];
        vf4 v2 = chan_base(x1, x2, b, c2)[off];
        vf4 v3 = chan_base(x1, x2, b, c3)[off];
        t0 += v0; t1 += v1; t2 += v2; t3 += v3;
        float h0 = (v0.x + v0.y) + (v0.z + v0.w);
        float h1 = (v1.x + v1.y) + (v1.z + v1.w);
        float h2 = (v2.x + v2.y) + (v2.z + v2.w);
        float h3 = (v3.x + v3.y) + (v3.z + v3.w);
        #pragma unroll
        for (int s = 16; s > 0; s >>= 1) {
            h0 += __shfl_down(h0, s, 32);
            h1 += __shfl_down(h1, s, 32);
            h2 += __shfl_down(h2, s, 32);
            h3 += __shfl_down(h3, s, 32);
        }
        if (slot == 0) { pp[c0] = h0; pp[c1] = h1; pp[c2] = h2; pp[c3] = h3; }
    }

    __shared__ vf4 red[8][32];
    red[g][slot] = (t0 + t1) + (t2 + t3);
    __syncthreads();
    if (g == 0) {
        vf4 r = (vf4)(0.f);
        #pragma unroll
        for (int gg = 0; gg < 8; ++gg) r += red[gg][slot];
        ((vf4*)(total + (size_t)b * HW))[off] = r;
    }
}

// ---------------------------------------------------------------------------
// K2: per-batch stable descending rank-sort (single dispatch, 16 blocks).
// ---------------------------------------------------------------------------
__global__ __launch_bounds__(512) void sort_kernel(
    const float* __restrict__ partials, int* __restrict__ idx)
{
    int b = blockIdx.x;
    int t = threadIdx.x;
    const float* pp = partials + (size_t)b * TCHUNK * C2 + t;
    float v = 0.f;
    #pragma unroll
    for (int ch = 0; ch < TCHUNK; ++ch) v += pp[ch * C2];
    __shared__ float sp[C2];
    sp[t] = v;
    __syncthreads();
    int rank = 0;
    for (int j = 0; j < C2; ++j) {
        float u = sp[j];
        rank += (u > v) || (u == v && j < t);
    }
    idx[b * C2 + rank] = t;
}

// ---------------------------------------------------------------------------
// K3: output (round-9 shape) with NONTEMPORAL out-stores: out bypasses L3,
// so the 128 MB of inputs stays L3-resident across replays (removes the
// steady-state 65 MB HBM re-fetch in K1) and halves per-replay HBM traffic.
// ---------------------------------------------------------------------------
__global__ __launch_bounds__(256) void output_kernel(
    const float* __restrict__ x1, const float* __restrict__ x2,
    const int* __restrict__ idx, const float* __restrict__ total,
    float* __restrict__ out, int k)
{
    int bid   = blockIdx.x;
    int b     = bid / TCHUNK;
    int chunk = bid % TCHUNK;
    int t     = threadIdx.x;
    int g     = t >> 5;
    int slot  = t & 31;
    int off   = chunk * 32 + slot;
    int nh    = k - 1;

    __shared__ int ch[C2 / 2];
    __shared__ vf4 red[8][32];
    for (int i = t; i < nh; i += 256) ch[i] = idx[b * C2 + i];
    __syncthreads();

    vf4 a0 = (vf4)(0.f), a1 = (vf4)(0.f), a2 = (vf4)(0.f), a3 = (vf4)(0.f);
    const size_t ob = (size_t)b * k;
    int r = g;
    for (; r + 24 < nh; r += 32) {
        int c0 = ch[r], c1 = ch[r + 8], c2 = ch[r + 16], c3 = ch[r + 24];
        vf4 v0 = chan_base(x1, x2, b, c0)[off];
        vf4 v1 = chan_base(x1, x2, b, c1)[off];
        vf4 v2 = chan_base(x1, x2, b, c2)[off];
        vf4 v3 = chan_base(x1, x2, b, c3)[off];
        __builtin_nontemporal_store(v0, (vf4*)(out + (ob + r     ) * HW) + off);
        __builtin_nontemporal_store(v1, (vf4*)(out + (ob + r +  8) * HW) + off);
        __builtin_nontemporal_store(v2, (vf4*)(out + (ob + r + 16) * HW) + off);
        __builtin_nontemporal_store(v3, (vf4*)(out + (ob + r + 24) * HW) + off);
        a0 += v0; a1 += v1; a2 += v2; a3 += v3;
    }
    for (; r < nh; r += 8) {
        int c0 = ch[r];
        vf4 v0 = chan_base(x1, x2, b, c0)[off];
        __builtin_nontemporal_store(v0, (vf4*)(out + (ob + r) * HW) + off);
        a0 += v0;
    }

    red[g][slot] = (a0 + a1) + (a2 + a3);
    __syncthreads();
    if (g == 0) {
        vf4 hsum = (vf4)(0.f);
        #pragma unroll
        for (int gg = 0; gg < 8; ++gg) hsum += red[gg][slot];
        vf4 tt = ((const vf4*)(total + (size_t)b * HW))[off];
        __builtin_nontemporal_store(tt - hsum,
                                    (vf4*)(out + (ob + (k - 1)) * HW) + off);
    }
}

// ---------------------------------------------------------------------------
extern "C" void kernel_launch(void* const* d_in, const int* in_sizes, int n_in,
                              void* d_out, int out_size, void* d_ws, size_t ws_size,
                              hipStream_t stream)
{
    const float* x1 = (const float*)d_in[0];
    const float* x2 = (const float*)d_in[1];
    float* out = (float*)d_out;

    int k = out_size / (B * HW);               // = 256

    int*   idx      = (int*)d_ws;
    float* total    = (float*)((char*)d_ws + B * C2 * sizeof(int));
    float* partials = total + (size_t)B * HW;

    reduce_kernel<<<B * TCHUNK, 256, 0, stream>>>(x1, x2, total, partials);
    sort_kernel<<<B, 512, 0, stream>>>(partials, idx);
    output_kernel<<<B * TCHUNK, 256, 0, stream>>>(x1, x2, idx, total, out, k);
}